// Round 1
// baseline (88.548 us; speedup 1.0000x reference)
//
#include <hip/hip_runtime.h>
#include <math.h>

#define BATCH   262144
#define CLUSTER 100

// Build a Lorentz boost matrix B = I - (g*mag)*nK + (g-1)*nK^2 analytically.
// With standard generators K_j: nK[0][j+1]=nK[j+1][0]=n_j, so
//   B[0][0]       = 1 + (g-1)*|n|^2
//   B[0][j+1]     = B[j+1][0] = -(g*mag)*n_j
//   B[i+1][j+1]   = delta_ij + (g-1)*n_i*n_j
__device__ inline void boost_mat(float bx, float by, float bz, float B[4][4]) {
    float m2  = bx * bx + by * by + bz * bz;
    float mag = sqrtf(m2);
    float nx = bx / mag, ny = by / mag, nz = bz / mag;
    float g  = 1.0f / sqrtf(1.0f - mag * mag);
    float gm = g * mag;
    float gm1 = g - 1.0f;
    float n[3] = {nx, ny, nz};
    B[0][0] = 1.0f + gm1 * (nx * nx + ny * ny + nz * nz);
    for (int j = 0; j < 3; ++j) {
        B[0][j + 1] = -gm * n[j];
        B[j + 1][0] = -gm * n[j];
    }
    for (int i = 0; i < 3; ++i)
        for (int j = 0; j < 3; ++j)
            B[i + 1][j + 1] = ((i == j) ? 1.0f : 0.0f) + gm1 * n[i] * n[j];
}

// Precompute M_c[a][d] = sum_e BiM[a][e] * (W_c * BoM_c[e][d]); store [c][a][d].
__global__ void build_M_kernel(const float* __restrict__ Bo,
                               const float* __restrict__ Bi,
                               const float* __restrict__ W,
                               float* __restrict__ M) {
    int c = threadIdx.x;
    if (c >= CLUSTER) return;

    float BiM[4][4];
    boost_mat(Bi[0], Bi[1], Bi[2], BiM);

    float BoM[4][4];
    boost_mat(Bo[c * 3 + 0], Bo[c * 3 + 1], Bo[c * 3 + 2], BoM);

    float w = W[c];
    for (int a = 0; a < 4; ++a)
        for (int d = 0; d < 4; ++d) {
            float s = 0.0f;
            for (int e = 0; e < 4; ++e)
                s += BiM[a][e] * (w * BoM[e][d]);
            M[c * 16 + a * 4 + d] = s;
        }
}

// Main: out[b][a] = sum_c sum_d M[c][a][d] * T[b][c][d]
// One wave handles 16 rows. Lane (4r+q) handles row r, clusters c = 4t+q.
// Global loads per instruction: 16 contiguous 64B segments (fully coalesced).
__global__ __launch_bounds__(256, 4) void lorentz_main_kernel(
        const float* __restrict__ T,
        const float* __restrict__ M,
        float* __restrict__ out) {
    __shared__ float sM[CLUSTER * 16];

    int tid = threadIdx.x;
    // stage M into LDS (400 float4s)
    for (int i = tid; i < CLUSTER * 4; i += 256)
        ((float4*)sM)[i] = ((const float4*)M)[i];
    __syncthreads();

    int wave = tid >> 6;
    int lane = tid & 63;
    int q  = lane & 3;
    int rl = lane >> 2;
    long long row = (long long)blockIdx.x * 64 + wave * 16 + rl;

    const float4* Trow = (const float4*)(T + row * (CLUSTER * 4));

    float ax = 0.0f, ay = 0.0f, az = 0.0f, aw = 0.0f;

    #pragma unroll 5
    for (int t = 0; t < 25; ++t) {
        int c = 4 * t + q;
        float4 v = Trow[t * 4 + q];  // = T[row][c][0..3]
        const float4* m = (const float4*)(sM + c * 16);
        float4 m0 = m[0], m1 = m[1], m2 = m[2], m3 = m[3];
        ax += m0.x * v.x + m0.y * v.y + m0.z * v.z + m0.w * v.w;
        ay += m1.x * v.x + m1.y * v.y + m1.z * v.z + m1.w * v.w;
        az += m2.x * v.x + m2.y * v.y + m2.z * v.z + m2.w * v.w;
        aw += m3.x * v.x + m3.y * v.y + m3.z * v.z + m3.w * v.w;
    }

    // reduce across the 4-lane group (q = 0..3)
    ax += __shfl_xor(ax, 1); ax += __shfl_xor(ax, 2);
    ay += __shfl_xor(ay, 1); ay += __shfl_xor(ay, 2);
    az += __shfl_xor(az, 1); az += __shfl_xor(az, 2);
    aw += __shfl_xor(aw, 1); aw += __shfl_xor(aw, 2);

    if (q == 0) {
        float4 o = {ax, ay, az, aw};
        ((float4*)out)[row] = o;
    }
}

extern "C" void kernel_launch(void* const* d_in, const int* in_sizes, int n_in,
                              void* d_out, int out_size, void* d_ws, size_t ws_size,
                              hipStream_t stream) {
    const float* T  = (const float*)d_in[0];
    const float* Bo = (const float*)d_in[1];
    const float* Bi = (const float*)d_in[2];
    const float* W  = (const float*)d_in[3];
    // d_in[4] = K_mats (structure folded into analytic boost formula)

    float* M = (float*)d_ws;           // 1600 floats
    float* out = (float*)d_out;

    build_M_kernel<<<1, 128, 0, stream>>>(Bo, Bi, W, M);

    int blocks = BATCH / 64;           // 64 rows per block (4 waves x 16 rows)
    lorentz_main_kernel<<<blocks, 256, 0, stream>>>(T, M, out);
}